// Round 2
// baseline (469.312 us; speedup 1.0000x reference)
//
#include <hip/hip_runtime.h>

// L_CA1 plus-phase: net = a_ECin@W_ECin + a_CA3@W_CA3 + a_ECout@W_ECout  [8192 x 64]
// act = relu(net)/(relu(net)+1); kWTA top-6 per row; out = activity + 0.1*(sparse - activity)
//
// v2: no inline asm. lane = row; W[k][c] is wave-uniform (compiler emits scalar
// loads; v_fmac vdst, s, v). A streamed per-lane as float4 (L1-resident row
// tiles, each A element fetched from HBM exactly once). K split x10 into
// deterministic partials in d_ws; 4-way interleaved accumulators + pairwise
// tree-sum to minimize accumulation-order divergence from the numpy reference
// (kWTA top-6 is discontinuous — flips, not smooth error, are the risk).

#define B_ROWS 8192
#define NCOL   64
#define KCHUNK 1024
#define NCHUNK 10   // 4 (ECin, K=4096) + 2 (CA3, K=2048) + 4 (ECout, K=4096)

// ---------------- GEMM partial kernel ----------------
// block = 256 threads = 4 waves. lane = row (64 rows per block), wave = 16-col
// slice (4 waves cover all 64 cols, sharing the same A rows through L1).

template<int KSEG>
__device__ __forceinline__ void gemm_chunk(const float* __restrict__ A,
                                           const float* __restrict__ W,
                                           float* __restrict__ P,
                                           int kof, int rb)
{
    const int lane = threadIdx.x & 63;
    const int wv   = __builtin_amdgcn_readfirstlane(threadIdx.x >> 6);
    const int c0   = wv * 16;                 // wave-uniform column base
    const int row  = rb * 64 + lane;

    const float* __restrict__ a = A + (size_t)row * KSEG + kof;   // per-lane
    const float* __restrict__ w = W + (size_t)kof * NCOL + c0;    // wave-uniform

    // 4 interleaved partial accumulators per column (k mod 4): ~2x smaller
    // rounding walk + different summation order than previous attempt.
    float p0[16], p1[16], p2[16], p3[16];
#pragma unroll
    for (int j = 0; j < 16; ++j) { p0[j] = 0.f; p1[j] = 0.f; p2[j] = 0.f; p3[j] = 0.f; }

#pragma unroll 2
    for (int t = 0; t < KCHUNK / 4; ++t) {
        const float4 av = *(const float4*)(a + 4 * t);    // A[row][k..k+3]
        const float* __restrict__ wt = w + (size_t)4 * t * NCOL;
#pragma unroll
        for (int j = 0; j < 16; ++j) p0[j] = fmaf(av.x, wt[j],            p0[j]);
#pragma unroll
        for (int j = 0; j < 16; ++j) p1[j] = fmaf(av.y, wt[NCOL + j],     p1[j]);
#pragma unroll
        for (int j = 0; j < 16; ++j) p2[j] = fmaf(av.z, wt[2 * NCOL + j], p2[j]);
#pragma unroll
        for (int j = 0; j < 16; ++j) p3[j] = fmaf(av.w, wt[3 * NCOL + j], p3[j]);
    }

    // pairwise tree-sum, then per-lane store of 16 consecutive floats
    // (compiler merges into dwordx4 stores).
    float* __restrict__ dst = P + (size_t)row * NCOL + c0;
#pragma unroll
    for (int j = 0; j < 16; ++j)
        dst[j] = (p0[j] + p1[j]) + (p2[j] + p3[j]);
}

__global__ __launch_bounds__(256, 4)
void gemm_kernel(const float* __restrict__ a_ECin,  const float* __restrict__ a_CA3,
                 const float* __restrict__ a_ECout, const float* __restrict__ W_ECin,
                 const float* __restrict__ W_CA3,   const float* __restrict__ W_ECout,
                 float* __restrict__ ws)
{
    const int bid   = blockIdx.x;
    const int chunk = bid >> 7;    // 0..9
    const int rb    = bid & 127;   // 0..127 row-blocks of 64
    float* P = ws + (size_t)chunk * (B_ROWS * NCOL);

    if (chunk < 4)      gemm_chunk<4096>(a_ECin,  W_ECin,  P, chunk * KCHUNK, rb);
    else if (chunk < 6) gemm_chunk<2048>(a_CA3,   W_CA3,   P, (chunk - 4) * KCHUNK, rb);
    else                gemm_chunk<4096>(a_ECout, W_ECout, P, (chunk - 6) * KCHUNK, rb);
}

// ---------------- epilogue: reduce partials + nxx1 + kWTA(6) + Euler ----------------
// wave = 64 lanes = 64 columns of one row; 4 rows per wave, 4 waves per block.

__global__ __launch_bounds__(256)
void epilogue_kernel(const float* __restrict__ ws,
                     const float* __restrict__ activity,
                     float* __restrict__ out)
{
    const int lane = threadIdx.x & 63;
    const int wv   = threadIdx.x >> 6;
    const int row0 = blockIdx.x * 16 + wv * 4;

#pragma unroll
    for (int rr = 0; rr < 4; ++rr) {
        const int row = row0 + rr;
        const size_t off = (size_t)row * NCOL + lane;

        // tree-sum the 10 chunk partials (deterministic, low rounding walk)
        float c[NCHUNK];
#pragma unroll
        for (int i = 0; i < NCHUNK; ++i)
            c[i] = ws[(size_t)i * (B_ROWS * NCOL) + off];
        const float t0 = c[0] + c[1], t1 = c[2] + c[3], t2 = c[4] + c[5],
                    t3 = c[6] + c[7], t4 = c[8] + c[9];
        const float net = ((t0 + t1) + (t2 + t3)) + t4;

        const float pos = fmaxf(net, 0.0f);
        const float act = pos / (pos + 1.0f);

        // 6th-largest of 64, duplicate-safe (mask exactly one lane per
        // extraction — matches lax.top_k count-duplicates semantics)
        float v = act, thr = 0.0f;
#pragma unroll
        for (int i = 0; i < 6; ++i) {
            float m = v;
#pragma unroll
            for (int off2 = 32; off2 >= 1; off2 >>= 1)
                m = fmaxf(m, __shfl_xor(m, off2, 64));
            const unsigned long long b = __ballot(v == m);
            const int first = __ffsll(b) - 1;
            if (lane == first) v = -__builtin_inff();
            thr = m;
        }

        const float sp = (act >= thr) ? act : 0.0f;
        const float a0 = activity[off];
        out[off] = fmaf(0.1f, sp - a0, a0);
    }
}

// ---------------- launcher ----------------
extern "C" void kernel_launch(void* const* d_in, const int* in_sizes, int n_in,
                              void* d_out, int out_size, void* d_ws, size_t ws_size,
                              hipStream_t stream)
{
    (void)in_sizes; (void)n_in; (void)out_size; (void)ws_size;
    const float* a_ECin   = (const float*)d_in[0];
    const float* a_CA3    = (const float*)d_in[1];
    const float* a_ECout  = (const float*)d_in[2];
    const float* W_ECin   = (const float*)d_in[3];
    const float* W_CA3    = (const float*)d_in[4];
    const float* W_ECout  = (const float*)d_in[5];
    const float* activity = (const float*)d_in[6];
    float* out = (float*)d_out;
    float* ws  = (float*)d_ws;   // 10 * 8192 * 64 * 4 = 20 MB

    hipLaunchKernelGGL(gemm_kernel, dim3(NCHUNK * 128), dim3(256), 0, stream,
                       a_ECin, a_CA3, a_ECout, W_ECin, W_CA3, W_ECout, ws);
    hipLaunchKernelGGL(epilogue_kernel, dim3(B_ROWS / 16), dim3(256), 0, stream,
                       ws, activity, out);
}